// Round 5
// baseline (366.806 us; speedup 1.0000x reference)
//
#include <hip/hip_runtime.h>

// One-level separable wavelet filterbank (maxflat), periodic extension.
// x: [8,3,1024,1024] f32 -> out: [4, 8,3,512,512] f32 (LL, LH, HL, HH)
//
// Round 8: direct dataflow (no LDS, no barriers) with HALF the per-thread
// footprint. Round-7 post-mortem: structure validated (VALUBusy 22.5%,
// 0 bank conflicts, FETCH 73.8 MB) but VGPR=180 capped residency at
// ~3 waves/CU (occupancy 9.8%) -> latency-bound, 92 us. Fix: 4 output
// cols per thread (acc 16 + 2x16-float row buffers live), VGPR capped
// at 128 via __launch_bounds__(256,4); 2x thread count restores the
// wave pool that hides the load latency.

constexpr int H = 1024, W = 1024;
constexpr int NIMG = 24;            // 8*3
constexpr int HOUT = 512, WOUT = 512;
constexpr int BROWS = 16;           // output rows per block (tid>>4)
constexpr int BCOLS = 64;           // output cols per block (16 groups of 4)

__global__ __launch_bounds__(256, 4)   // cap VGPR at 128; live state ~50 floats
void wfb_kernel(const float* __restrict__ x, float* __restrict__ out) {
    // h (len 5, ext 2) and h1 (len 7, ext 4), exact maxflat values
    const float h0c[5] = {0.125f, 0.35355339059327373f, 1.25f,
                          0.35355339059327373f, 0.125f};
    const float h1c[7] = {0.025888347648318447f,  0.07322330470336313f,
                          -0.06878156646177083f, -0.8535533905932737f,
                          -0.06878156646177083f,  0.07322330470336313f,
                          0.025888347648318447f};

    const int tid = threadIdx.x;
    const int img = blockIdx.z;
    const int R  = blockIdx.y * BROWS + (tid >> 4);        // global output row
    const int J0 = blockIdx.x * BCOLS + (tid & 15) * 4;    // first of 4 out cols
    const float* __restrict__ xin = x + (size_t)img * H * W;

    const int rb = 2 * R - 4;        // first input row (7 needed: rb..rb+6)
    const int cb = 2 * J0 - 4;       // first input col (13 used, 16 loaded)
                                     // cb % 4 == 0 -> float4-aligned

    float LL[4] = {0,0,0,0}, LH[4] = {0,0,0,0};
    float HL[4] = {0,0,0,0}, HH[4] = {0,0,0,0};

    auto LOADROW = [&](int d, float* v) {
        const int gr = (rb + d) & (H - 1);                // periodic rows
        const float* __restrict__ rowp = xin + (size_t)gr * W;
        #pragma unroll
        for (int q = 0; q < 4; ++q) {
            int gc = (cb + 4 * q) & (W - 1);              // periodic, 16B-align
            float4 f = *(const float4*)(rowp + gc);
            v[4*q + 0] = f.x; v[4*q + 1] = f.y;
            v[4*q + 2] = f.z; v[4*q + 3] = f.w;
        }
    };

    // row-filter input row d, then accumulate its column-filter contribution.
    // LH/HH use h1c[d] (7-tap, d=0..6); LL/HL use h0c[d-2] (5-tap, d=2..6).
    auto STEP = [&](int d, const float* v) {
        #pragma unroll
        for (int u = 0; u < 4; ++u) {
            const float* p = v + 2 * u;
            float Lr = h0c[0]*p[2] + h0c[1]*p[3] + h0c[2]*p[4]
                     + h0c[3]*p[5] + h0c[4]*p[6];
            float Hr = h1c[0]*p[0] + h1c[1]*p[1] + h1c[2]*p[2] + h1c[3]*p[3]
                     + h1c[4]*p[4] + h1c[5]*p[5] + h1c[6]*p[6];
            LH[u] += h1c[d] * Lr;
            HH[u] += h1c[d] * Hr;
            if (d >= 2) {
                LL[u] += h0c[d-2] * Lr;
                HL[u] += h0c[d-2] * Hr;
            }
        }
    };

    // ---- 2-deep register double buffer over the 7 input rows ----
    float va[16], vb[16];
    LOADROW(0, va);
    LOADROW(1, vb);
    STEP(0, va);  LOADROW(2, va);
    STEP(1, vb);  LOADROW(3, vb);
    STEP(2, va);  LOADROW(4, va);
    STEP(3, vb);  LOADROW(5, vb);
    STEP(4, va);  LOADROW(6, va);
    STEP(5, vb);
    STEP(6, va);

    // ---- stores: 1 float4 per subband ----
    constexpr size_t SB = (size_t)NIMG * HOUT * WOUT;     // per-subband stride
    float* __restrict__ o = out + (size_t)img * HOUT * WOUT;
    const size_t off = (size_t)R * WOUT + J0;
    *(float4*)(o + 0*SB + off) = make_float4(LL[0], LL[1], LL[2], LL[3]);
    *(float4*)(o + 1*SB + off) = make_float4(LH[0], LH[1], LH[2], LH[3]);
    *(float4*)(o + 2*SB + off) = make_float4(HL[0], HL[1], HL[2], HL[3]);
    *(float4*)(o + 3*SB + off) = make_float4(HH[0], HH[1], HH[2], HH[3]);
}

extern "C" void kernel_launch(void* const* d_in, const int* in_sizes, int n_in,
                              void* d_out, int out_size, void* d_ws, size_t ws_size,
                              hipStream_t stream) {
    const float* x = (const float*)d_in[0];
    float* out = (float*)d_out;
    dim3 grid(WOUT / BCOLS, HOUT / BROWS, NIMG);   // 8 x 32 x 24
    wfb_kernel<<<grid, dim3(256), 0, stream>>>(x, out);
}

// Round 6
// 195.227 us; speedup vs baseline: 1.8789x; 1.8789x over previous
//
#include <hip/hip_runtime.h>

// One-level separable wavelet filterbank (maxflat), periodic extension.
// x: [8,3,1024,1024] f32 -> out: [4, 8,3,512,512] f32 (LL, LH, HL, HH)
//
// Round 9: direct dataflow (no LDS, no barriers), UNPINNED, small footprint.
// Round-8 post-mortem: __launch_bounds__(256,4) made the allocator force
// VGPR=64 and spill (WRITE 98->634 MB). Rule: never pin waves/EU here.
// Round-7 anchor: unpinned dataflow is occupancy-starved at VGPR=180.
// This round shrinks live state algorithmically: 4 output cols/thread and
// VERTICAL-FIRST separable factorization — accumulate col-filter partials
// vA (col-low) / vB (col-high) over the 7 input rows, then apply the two
// horizontal filters once. Live: vA[16]+vB[16]+2x16 row buffers = 64
// floats -> ~100 VGPR unpinned -> 4 waves/SIMD; ~33% fewer FMAs too.

constexpr int H = 1024, W = 1024;
constexpr int NIMG = 24;            // 8*3
constexpr int HOUT = 512, WOUT = 512;
constexpr int BROWS = 16;           // output rows per block (tid>>4)
constexpr int BCOLS = 64;           // output cols per block (16 groups of 4)

__global__ __launch_bounds__(256)
void wfb_kernel(const float* __restrict__ x, float* __restrict__ out) {
    // h (len 5, ext 2) and h1 (len 7, ext 4), exact maxflat values
    const float h0c[5] = {0.125f, 0.35355339059327373f, 1.25f,
                          0.35355339059327373f, 0.125f};
    const float h1c[7] = {0.025888347648318447f,  0.07322330470336313f,
                          -0.06878156646177083f, -0.8535533905932737f,
                          -0.06878156646177083f,  0.07322330470336313f,
                          0.025888347648318447f};

    const int tid = threadIdx.x;
    const int img = blockIdx.z;
    const int R  = blockIdx.y * BROWS + (tid >> 4);        // global output row
    const int J0 = blockIdx.x * BCOLS + (tid & 15) * 4;    // first of 4 out cols
    const float* __restrict__ xin = x + (size_t)img * H * W;

    const int rb = 2 * R - 4;        // first input row (7 needed: rb..rb+6)
    const int cb = 2 * J0 - 4;       // first input col (13 used, 16 loaded)
                                     // cb % 4 == 0 -> float4-aligned

    float vA[16], vB[16];            // col-low / col-high partials
    #pragma unroll
    for (int c = 0; c < 16; ++c) { vA[c] = 0.f; vB[c] = 0.f; }

    auto LOADROW = [&](int d, float* v) {
        const int gr = (rb + d) & (H - 1);                // periodic rows
        const float* __restrict__ rowp = xin + (size_t)gr * W;
        #pragma unroll
        for (int q = 0; q < 4; ++q) {
            int gc = (cb + 4 * q) & (W - 1);              // periodic, 16B-align
            float4 f = *(const float4*)(rowp + gc);
            v[4*q + 0] = f.x; v[4*q + 1] = f.y;
            v[4*q + 2] = f.z; v[4*q + 3] = f.w;
        }
    };

    // vertical accumulation: vB (7-tap h1, d=0..6), vA (5-tap h0, d=2..6)
    auto ACC = [&](int d, const float* v) {
        #pragma unroll
        for (int c = 0; c < 16; ++c) {
            vB[c] += h1c[d] * v[c];
            if (d >= 2) vA[c] += h0c[d-2] * v[c];
        }
    };

    // ---- 2-deep register double buffer over the 7 input rows ----
    float va[16], vb[16];
    LOADROW(0, va);
    LOADROW(1, vb);
    ACC(0, va);  LOADROW(2, va);
    ACC(1, vb);  LOADROW(3, vb);
    ACC(2, va);  LOADROW(4, va);
    ACC(3, vb);  LOADROW(5, vb);
    ACC(4, va);  LOADROW(6, va);
    ACC(5, vb);
    ACC(6, va);

    // ---- horizontal filters on the vertical partials ----
    float LL[4], LH[4], HL[4], HH[4];
    #pragma unroll
    for (int u = 0; u < 4; ++u) {
        const float* a = vA + 2 * u;     // a[i] = vA[2u+i]
        const float* b = vB + 2 * u;
        LL[u] = h0c[0]*a[2] + h0c[1]*a[3] + h0c[2]*a[4]
              + h0c[3]*a[5] + h0c[4]*a[6];
        HL[u] = h1c[0]*a[0] + h1c[1]*a[1] + h1c[2]*a[2] + h1c[3]*a[3]
              + h1c[4]*a[4] + h1c[5]*a[5] + h1c[6]*a[6];
        LH[u] = h0c[0]*b[2] + h0c[1]*b[3] + h0c[2]*b[4]
              + h0c[3]*b[5] + h0c[4]*b[6];
        HH[u] = h1c[0]*b[0] + h1c[1]*b[1] + h1c[2]*b[2] + h1c[3]*b[3]
              + h1c[4]*b[4] + h1c[5]*b[5] + h1c[6]*b[6];
    }

    // ---- stores: 1 float4 per subband ----
    constexpr size_t SB = (size_t)NIMG * HOUT * WOUT;     // per-subband stride
    float* __restrict__ o = out + (size_t)img * HOUT * WOUT;
    const size_t off = (size_t)R * WOUT + J0;
    *(float4*)(o + 0*SB + off) = make_float4(LL[0], LL[1], LL[2], LL[3]);
    *(float4*)(o + 1*SB + off) = make_float4(LH[0], LH[1], LH[2], LH[3]);
    *(float4*)(o + 2*SB + off) = make_float4(HL[0], HL[1], HL[2], HL[3]);
    *(float4*)(o + 3*SB + off) = make_float4(HH[0], HH[1], HH[2], HH[3]);
}

extern "C" void kernel_launch(void* const* d_in, const int* in_sizes, int n_in,
                              void* d_out, int out_size, void* d_ws, size_t ws_size,
                              hipStream_t stream) {
    const float* x = (const float*)d_in[0];
    float* out = (float*)d_out;
    dim3 grid(WOUT / BCOLS, HOUT / BROWS, NIMG);   // 8 x 32 x 24
    wfb_kernel<<<grid, dim3(256), 0, stream>>>(x, out);
}

// Round 8
// 187.731 us; speedup vs baseline: 1.9539x; 1.0399x over previous
//
#include <hip/hip_runtime.h>

// One-level separable wavelet filterbank (maxflat), periodic extension.
// x: [8,3,1024,1024] f32 -> out: [4, 8,3,512,512] f32 (LL, LH, HL, HH)
//
// Round 10 (resubmit; round-7-of-session bench was an infra failure, the
// kernel never ran): dataflow kernel tuned to the 64-VGPR occupancy cliff.
// Round-9 post-mortem: VGPR=68 -> 4 waves/SIMD (cap at 65-128); achieved
// occ 22%, latency-bound at 78 us. This round sheds 22 live floats
// algorithmically (NO __launch_bounds__ pin - rounds 5/8 showed pins
// spill): (1) single v[16] row buffer instead of double buffer (WAR dep
// serializes rows; within-wave overlap only hid ~100 of ~650 cy anyway),
// (2) accumulators trimmed to the 13 used entries vA[0..12]/vB[0..12].
// Live = 42 floats + addressing -> target <=64 VGPR = 8 waves/SIMD.

constexpr int H = 1024, W = 1024;
constexpr int NIMG = 24;            // 8*3
constexpr int HOUT = 512, WOUT = 512;
constexpr int BROWS = 16;           // output rows per block (tid>>4)
constexpr int BCOLS = 64;           // output cols per block (16 groups of 4)

__global__ __launch_bounds__(256)
void wfb_kernel(const float* __restrict__ x, float* __restrict__ out) {
    // h (len 5, ext 2) and h1 (len 7, ext 4), exact maxflat values
    const float h0c[5] = {0.125f, 0.35355339059327373f, 1.25f,
                          0.35355339059327373f, 0.125f};
    const float h1c[7] = {0.025888347648318447f,  0.07322330470336313f,
                          -0.06878156646177083f, -0.8535533905932737f,
                          -0.06878156646177083f,  0.07322330470336313f,
                          0.025888347648318447f};

    const int tid = threadIdx.x;
    const int img = blockIdx.z;
    const int R  = blockIdx.y * BROWS + (tid >> 4);        // global output row
    const int J0 = blockIdx.x * BCOLS + (tid & 15) * 4;    // first of 4 out cols
    const float* __restrict__ xin = x + (size_t)img * H * W;

    const int rb = 2 * R - 4;        // first input row (7 needed: rb..rb+6)
    const int cb = 2 * J0 - 4;       // first input col; cb%4==0 -> f4-aligned

    // periodic column offsets are row-invariant: compute once
    int gc0 = (cb     ) & (W - 1);
    int gc1 = (cb +  4) & (W - 1);
    int gc2 = (cb +  8) & (W - 1);
    int gc3 = (cb + 12) & (W - 1);

    float vA[13], vB[13];            // col-low / col-high partials (13 used)
    #pragma unroll
    for (int c = 0; c < 13; ++c) { vA[c] = 0.f; vB[c] = 0.f; }

    float v[16];                     // SINGLE row buffer, reused all 7 rows

    #pragma unroll
    for (int d = 0; d < 7; ++d) {
        const int gr = (rb + d) & (H - 1);                 // periodic rows
        const float* __restrict__ rowp = xin + ((size_t)gr << 10);
        {
            float4 f0 = *(const float4*)(rowp + gc0);
            float4 f1 = *(const float4*)(rowp + gc1);
            float4 f2 = *(const float4*)(rowp + gc2);
            float4 f3 = *(const float4*)(rowp + gc3);
            v[ 0]=f0.x; v[ 1]=f0.y; v[ 2]=f0.z; v[ 3]=f0.w;
            v[ 4]=f1.x; v[ 5]=f1.y; v[ 6]=f1.z; v[ 7]=f1.w;
            v[ 8]=f2.x; v[ 9]=f2.y; v[10]=f2.z; v[11]=f2.w;
            v[12]=f3.x;                       // v[13..15] of f3 unused
        }
        #pragma unroll
        for (int c = 0; c < 13; ++c) {
            vB[c] += h1c[d] * v[c];
        }
        if (d >= 2) {
            #pragma unroll
            for (int c = 0; c < 13; ++c) {
                vA[c] += h0c[d - 2] * v[c];
            }
        }
    }

    // ---- horizontal filters on the vertical partials ----
    float LL[4], LH[4], HL[4], HH[4];
    #pragma unroll
    for (int u = 0; u < 4; ++u) {
        const float* a = vA + 2 * u;     // a[i] = vA[2u+i], max idx 12
        const float* b = vB + 2 * u;
        LL[u] = h0c[0]*a[2] + h0c[1]*a[3] + h0c[2]*a[4]
              + h0c[3]*a[5] + h0c[4]*a[6];
        HL[u] = h1c[0]*a[0] + h1c[1]*a[1] + h1c[2]*a[2] + h1c[3]*a[3]
              + h1c[4]*a[4] + h1c[5]*a[5] + h1c[6]*a[6];
        LH[u] = h0c[0]*b[2] + h0c[1]*b[3] + h0c[2]*b[4]
              + h0c[3]*b[5] + h0c[4]*b[6];
        HH[u] = h1c[0]*b[0] + h1c[1]*b[1] + h1c[2]*b[2] + h1c[3]*b[3]
              + h1c[4]*b[4] + h1c[5]*b[5] + h1c[6]*b[6];
    }

    // ---- stores: 1 float4 per subband ----
    constexpr size_t SB = (size_t)NIMG * HOUT * WOUT;     // per-subband stride
    float* __restrict__ o = out + (size_t)img * HOUT * WOUT;
    const size_t off = (size_t)R * WOUT + J0;
    *(float4*)(o + 0*SB + off) = make_float4(LL[0], LL[1], LL[2], LL[3]);
    *(float4*)(o + 1*SB + off) = make_float4(LH[0], LH[1], LH[2], LH[3]);
    *(float4*)(o + 2*SB + off) = make_float4(HL[0], HL[1], HL[2], HL[3]);
    *(float4*)(o + 3*SB + off) = make_float4(HH[0], HH[1], HH[2], HH[3]);
}

extern "C" void kernel_launch(void* const* d_in, const int* in_sizes, int n_in,
                              void* d_out, int out_size, void* d_ws, size_t ws_size,
                              hipStream_t stream) {
    const float* x = (const float*)d_in[0];
    float* out = (float*)d_out;
    dim3 grid(WOUT / BCOLS, HOUT / BROWS, NIMG);   // 8 x 32 x 24
    wfb_kernel<<<grid, dim3(256), 0, stream>>>(x, out);
}

// Round 9
// 175.822 us; speedup vs baseline: 2.0862x; 1.0677x over previous
//
#include <hip/hip_runtime.h>

// One-level separable wavelet filterbank (maxflat), periodic extension.
// x: [8,3,1024,1024] f32 -> out: [4, 8,3,512,512] f32 (LL, LH, HL, HH)
//
// Round 11: async-staged LDS tile + vertical-first register compute.
// Rounds 7-10 post-mortem: all pure-dataflow variants are MLP-bound
// (7-round serial load chain x ~8 resident waves ~= 31 KB in flight);
// round-8's spill kernel proved the chip does 4 TB/s here. Fix: stage
// the 37x144-float input tile into LDS via global_load_lds (21 wave
// instructions, ALL in flight at once, no VGPR cost, no dep chain),
// one barrier, then the validated vertical-first compute reads LDS
// (~120 cy) instead of L3 (~600 cy). LDS 21.5 KB -> 7 blocks/CU.
// Known cost: compute ds_read at lane-stride 32B = 4-way conflict
// (1.58x, m136) - accepted; revisit with swizzle only if it dominates.

constexpr int H = 1024, W = 1024;
constexpr int NIMG = 24;            // 8*3
constexpr int HOUT = 512, WOUT = 512;
constexpr int BROWS = 16;           // output rows per block (tid>>4)
constexpr int BCOLS = 64;           // output cols per block (16 groups of 4)
constexpr int TROWS = 37;           // staged input rows: 2*15 + 7 taps
constexpr int TSEGS = 36;           // 16B segs per staged row (34 used, 2 pad)
constexpr int NSEG  = TROWS * TSEGS;         // 1332
constexpr int NCHUNK = (NSEG + 63) / 64;     // 21 chunks of 64 segs (1024B)
constexpr int ROWF  = TSEGS * 4;             // 144 floats per LDS row

__global__ __launch_bounds__(256)
void wfb_kernel(const float* __restrict__ x, float* __restrict__ out) {
    __shared__ __align__(16) float smem[NCHUNK * 256];   // 21504 B

    // h (len 5, ext 2) and h1 (len 7, ext 4), exact maxflat values
    const float h0c[5] = {0.125f, 0.35355339059327373f, 1.25f,
                          0.35355339059327373f, 0.125f};
    const float h1c[7] = {0.025888347648318447f,  0.07322330470336313f,
                          -0.06878156646177083f, -0.8535533905932737f,
                          -0.06878156646177083f,  0.07322330470336313f,
                          0.025888347648318447f};

    const int tid  = threadIdx.x;
    const int wave = tid >> 6;          // 0..3, wave-uniform
    const int lane = tid & 63;
    const int img  = blockIdx.z;
    const int R0   = blockIdx.y * BROWS;
    const int J0b  = blockIdx.x * BCOLS;
    const float* __restrict__ xin = x + (size_t)img * H * W;
    const int rb0 = 2 * R0 - 4;         // first staged input row
    const int cb0 = 2 * J0b - 4;        // first staged input col; %4==0 -> 16B

    // ---- stage: 21 direct-to-LDS wave loads, all independent, in flight ----
    // LDS dest = wave-uniform base + lane*16 (HW rule); global src per-lane.
    // Seg t = c*64+lane maps to tile (r = t/36, s = t%36); segs s=34,35 and
    // the r=37 tail are wrapped junk (valid addresses, never read).
    for (int c = wave; c < NCHUNK; c += 4) {
        int t  = c * 64 + lane;
        int r  = t / TSEGS;
        int s  = t - r * TSEGS;
        int gr = (rb0 + r) & (H - 1);               // periodic rows
        int gc = (cb0 + 4 * s) & (W - 1);           // periodic, keeps 16B align
        const float* gp = xin + ((size_t)gr << 10) + gc;
        __builtin_amdgcn_global_load_lds(
            (const __attribute__((address_space(1))) void*)gp,
            (__attribute__((address_space(3))) void*)(smem + c * 256),
            16, 0, 0);
    }
    __syncthreads();   // compiler drains vmcnt before s_barrier

    // ---- compute: vertical-first from LDS (round-10 structure) ----
    const int Rl   = tid >> 4;          // 0..15 output row in tile
    const int colf = (tid & 15) * 8;    // first input-col float offset in row

    float vA[13], vB[13];               // col-low / col-high partials
    #pragma unroll
    for (int c = 0; c < 13; ++c) { vA[c] = 0.f; vB[c] = 0.f; }

    #pragma unroll
    for (int d = 0; d < 7; ++d) {
        const float* rowp = smem + (2 * Rl + d) * ROWF + colf;
        float4 f0 = *(const float4*)(rowp);
        float4 f1 = *(const float4*)(rowp + 4);
        float4 f2 = *(const float4*)(rowp + 8);
        float v12 = rowp[12];
        float v[13] = {f0.x, f0.y, f0.z, f0.w,
                       f1.x, f1.y, f1.z, f1.w,
                       f2.x, f2.y, f2.z, f2.w, v12};
        #pragma unroll
        for (int c = 0; c < 13; ++c) vB[c] += h1c[d] * v[c];
        if (d >= 2) {
            #pragma unroll
            for (int c = 0; c < 13; ++c) vA[c] += h0c[d - 2] * v[c];
        }
    }

    // ---- horizontal filters on the vertical partials ----
    float LL[4], LH[4], HL[4], HH[4];
    #pragma unroll
    for (int u = 0; u < 4; ++u) {
        const float* a = vA + 2 * u;     // max idx 12
        const float* b = vB + 2 * u;
        LL[u] = h0c[0]*a[2] + h0c[1]*a[3] + h0c[2]*a[4]
              + h0c[3]*a[5] + h0c[4]*a[6];
        HL[u] = h1c[0]*a[0] + h1c[1]*a[1] + h1c[2]*a[2] + h1c[3]*a[3]
              + h1c[4]*a[4] + h1c[5]*a[5] + h1c[6]*a[6];
        LH[u] = h0c[0]*b[2] + h0c[1]*b[3] + h0c[2]*b[4]
              + h0c[3]*b[5] + h0c[4]*b[6];
        HH[u] = h1c[0]*b[0] + h1c[1]*b[1] + h1c[2]*b[2] + h1c[3]*b[3]
              + h1c[4]*b[4] + h1c[5]*b[5] + h1c[6]*b[6];
    }

    // ---- stores: 1 float4 per subband ----
    constexpr size_t SB = (size_t)NIMG * HOUT * WOUT;     // per-subband stride
    float* __restrict__ o = out + (size_t)img * HOUT * WOUT;
    const int R  = R0 + Rl;
    const int J0 = J0b + (tid & 15) * 4;
    const size_t off = (size_t)R * WOUT + J0;
    *(float4*)(o + 0*SB + off) = make_float4(LL[0], LL[1], LL[2], LL[3]);
    *(float4*)(o + 1*SB + off) = make_float4(LH[0], LH[1], LH[2], LH[3]);
    *(float4*)(o + 2*SB + off) = make_float4(HL[0], HL[1], HL[2], HL[3]);
    *(float4*)(o + 3*SB + off) = make_float4(HH[0], HH[1], HH[2], HH[3]);
}

extern "C" void kernel_launch(void* const* d_in, const int* in_sizes, int n_in,
                              void* d_out, int out_size, void* d_ws, size_t ws_size,
                              hipStream_t stream) {
    const float* x = (const float*)d_in[0];
    float* out = (float*)d_out;
    dim3 grid(WOUT / BCOLS, HOUT / BROWS, NIMG);   // 8 x 32 x 24
    wfb_kernel<<<grid, dim3(256), 0, stream>>>(x, out);
}

// Round 10
// 173.122 us; speedup vs baseline: 2.1188x; 1.0156x over previous
//
#include <hip/hip_runtime.h>

// One-level separable wavelet filterbank (maxflat), periodic extension.
// x: [8,3,1024,1024] f32 -> out: [4, 8,3,512,512] f32 (LL, LH, HL, HH)
//
// Round 12: round-11 staged kernel + seg-XOR LDS swizzle.
// Round-11 post-mortem: ds_read pattern was a 16-WAY bank conflict
// (lane stride 32B -> quads {0,8,16,24}; row-groups at dr=2 alias the
// same quads since 2*144 mod 32 = 0) -> SQ_LDS_BANK_CONFLICT 22.5M,
// ~70% of kernel cycles. Fix (T2, both-sides-or-neither): swizzle at
// 16B-seg granularity with e(r) = (r>>1)&1 — staging pre-swizzles the
// GLOBAL source column (LDS dest must stay linear for global_load_lds),
// reads XOR the seg index. Adjacent row-groups then hit disjoint bank
// halves: 8 lanes/bank = wave64 b128 hardware minimum.

constexpr int H = 1024, W = 1024;
constexpr int NIMG = 24;            // 8*3
constexpr int HOUT = 512, WOUT = 512;
constexpr int BROWS = 16;           // output rows per block (tid>>4)
constexpr int BCOLS = 64;           // output cols per block (16 groups of 4)
constexpr int TROWS = 37;           // staged input rows: 2*15 + 7 taps
constexpr int TSEGS = 36;           // 16B segs per staged row (34 used, 2 pad)
constexpr int NSEG  = TROWS * TSEGS;         // 1332
constexpr int NCHUNK = (NSEG + 63) / 64;     // 21 chunks of 64 segs (1024B)
constexpr int ROWF  = TSEGS * 4;             // 144 floats per LDS row

__global__ __launch_bounds__(256)
void wfb_kernel(const float* __restrict__ x, float* __restrict__ out) {
    __shared__ __align__(16) float smem[NCHUNK * 256];   // 21504 B

    // h (len 5, ext 2) and h1 (len 7, ext 4), exact maxflat values
    const float h0c[5] = {0.125f, 0.35355339059327373f, 1.25f,
                          0.35355339059327373f, 0.125f};
    const float h1c[7] = {0.025888347648318447f,  0.07322330470336313f,
                          -0.06878156646177083f, -0.8535533905932737f,
                          -0.06878156646177083f,  0.07322330470336313f,
                          0.025888347648318447f};

    const int tid  = threadIdx.x;
    const int wave = tid >> 6;          // 0..3, wave-uniform
    const int lane = tid & 63;
    const int img  = blockIdx.z;
    const int R0   = blockIdx.y * BROWS;
    const int J0b  = blockIdx.x * BCOLS;
    const float* __restrict__ xin = x + (size_t)img * H * W;
    const int rb0 = 2 * R0 - 4;         // first staged input row
    const int cb0 = 2 * J0b - 4;        // first staged input col; %4==0 -> 16B

    // ---- stage: direct-to-LDS wave loads, source pre-swizzled ----
    // LDS seg u=(r,s_lds) receives global seg s_lds ^ e(r), e(r)=(r>>1)&1.
    // XOR by 1 keeps segs inside the 36-seg row and preserves 16B align.
    for (int c = wave; c < NCHUNK; c += 4) {
        int t  = c * 64 + lane;
        int r  = t / TSEGS;
        int s  = t - r * TSEGS;
        int e  = (r >> 1) & 1;
        int gr = (rb0 + r) & (H - 1);               // periodic rows
        int gc = (cb0 + 4 * (s ^ e)) & (W - 1);     // periodic, 16B align kept
        const float* gp = xin + ((size_t)gr << 10) + gc;
        __builtin_amdgcn_global_load_lds(
            (const __attribute__((address_space(1))) void*)gp,
            (__attribute__((address_space(3))) void*)(smem + c * 256),
            16, 0, 0);
    }
    __syncthreads();   // compiler drains vmcnt before s_barrier

    // ---- compute: vertical-first from LDS, reads de-swizzle ----
    const int Rl = tid >> 4;            // 0..15 output row in tile
    const int s0 = (tid & 15) * 2;      // first logical seg (even)

    float vA[13], vB[13];               // col-low / col-high partials
    #pragma unroll
    for (int c = 0; c < 13; ++c) { vA[c] = 0.f; vB[c] = 0.f; }

    #pragma unroll
    for (int d = 0; d < 7; ++d) {
        const int r = 2 * Rl + d;
        const int e = (r >> 1) & 1;     // alternates across row-groups
        const float* base = smem + r * ROWF;
        // logical seg s is stored at LDS seg s^e; seg -> float offset = *4
        float4 f0 = *(const float4*)(base + (((s0    ) ^ e) << 2));
        float4 f1 = *(const float4*)(base + (((s0 + 1) ^ e) << 2));
        float4 f2 = *(const float4*)(base + (((s0 + 2) ^ e) << 2));
        float v12 = base[((s0 + 3) ^ e) << 2];
        float v[13] = {f0.x, f0.y, f0.z, f0.w,
                       f1.x, f1.y, f1.z, f1.w,
                       f2.x, f2.y, f2.z, f2.w, v12};
        #pragma unroll
        for (int c = 0; c < 13; ++c) vB[c] += h1c[d] * v[c];
        if (d >= 2) {
            #pragma unroll
            for (int c = 0; c < 13; ++c) vA[c] += h0c[d - 2] * v[c];
        }
    }

    // ---- horizontal filters on the vertical partials ----
    float LL[4], LH[4], HL[4], HH[4];
    #pragma unroll
    for (int u = 0; u < 4; ++u) {
        const float* a = vA + 2 * u;     // max idx 12
        const float* b = vB + 2 * u;
        LL[u] = h0c[0]*a[2] + h0c[1]*a[3] + h0c[2]*a[4]
              + h0c[3]*a[5] + h0c[4]*a[6];
        HL[u] = h1c[0]*a[0] + h1c[1]*a[1] + h1c[2]*a[2] + h1c[3]*a[3]
              + h1c[4]*a[4] + h1c[5]*a[5] + h1c[6]*a[6];
        LH[u] = h0c[0]*b[2] + h0c[1]*b[3] + h0c[2]*b[4]
              + h0c[3]*b[5] + h0c[4]*b[6];
        HH[u] = h1c[0]*b[0] + h1c[1]*b[1] + h1c[2]*b[2] + h1c[3]*b[3]
              + h1c[4]*b[4] + h1c[5]*b[5] + h1c[6]*b[6];
    }

    // ---- stores: 1 float4 per subband ----
    constexpr size_t SB = (size_t)NIMG * HOUT * WOUT;     // per-subband stride
    float* __restrict__ o = out + (size_t)img * HOUT * WOUT;
    const int R  = R0 + Rl;
    const int J0 = J0b + (tid & 15) * 4;
    const size_t off = (size_t)R * WOUT + J0;
    *(float4*)(o + 0*SB + off) = make_float4(LL[0], LL[1], LL[2], LL[3]);
    *(float4*)(o + 1*SB + off) = make_float4(LH[0], LH[1], LH[2], LH[3]);
    *(float4*)(o + 2*SB + off) = make_float4(HL[0], HL[1], HL[2], HL[3]);
    *(float4*)(o + 3*SB + off) = make_float4(HH[0], HH[1], HH[2], HH[3]);
}

extern "C" void kernel_launch(void* const* d_in, const int* in_sizes, int n_in,
                              void* d_out, int out_size, void* d_ws, size_t ws_size,
                              hipStream_t stream) {
    const float* x = (const float*)d_in[0];
    float* out = (float*)d_out;
    dim3 grid(WOUT / BCOLS, HOUT / BROWS, NIMG);   // 8 x 32 x 24
    wfb_kernel<<<grid, dim3(256), 0, stream>>>(x, out);
}